// Round 1
// baseline (662.148 us; speedup 1.0000x reference)
//
#include <hip/hip_runtime.h>

#define BB 2
#define SS 2048
#define DD 1024
#define NH 16
#define NKVH 4
#define GRP 4
#define HD 64
#define SCALE 0.125f   // 64^-0.5
#define NEGBIG -1e9f

typedef __bf16 bf16;
typedef __bf16 bf16x8 __attribute__((ext_vector_type(8)));
typedef float floatx4 __attribute__((ext_vector_type(4)));

// ---------- prep kernels ----------
__global__ void cast_bf16_kernel(const float* __restrict__ x, bf16* __restrict__ y, int n) {
    int i = blockIdx.x * blockDim.x + threadIdx.x;
    if (i < n) y[i] = (bf16)x[i];
}

// Wt[n][k] = W[k][n], fp32 -> bf16.  W is K x N row-major.
__global__ void transpose_cast_kernel(const float* __restrict__ W, bf16* __restrict__ Wt,
                                      int K, int N) {
    int i = blockIdx.x * blockDim.x + threadIdx.x;
    if (i >= K * N) return;
    int k = i / N, n = i - k * N;
    Wt[(size_t)n * K + k] = (bf16)W[i];
}

// ---------- GEMM: C[M,N] = A[M,K] * Bt[N,K]^T (bf16 in, fp32 acc) ----------
// one wave per 16x16 C tile; block = 4 waves covering 64 N-columns.
__global__ __launch_bounds__(256) void gemm_bt(const bf16* __restrict__ A,
                                               const bf16* __restrict__ Bt,
                                               bf16* __restrict__ Cb,
                                               float* __restrict__ Cf,
                                               int M, int N, int K) {
    int wave = threadIdx.x >> 6;
    int lane = threadIdx.x & 63;
    int lm   = lane & 15;
    int quad = lane >> 4;
    int m0 = blockIdx.x * 16;
    int n0 = blockIdx.y * 64 + wave * 16;
    if (m0 >= M || n0 >= N) return;

    const bf16* ap = A  + (size_t)(m0 + lm) * K + quad * 8;
    const bf16* bp = Bt + (size_t)(n0 + lm) * K + quad * 8;

    floatx4 acc = {0.f, 0.f, 0.f, 0.f};
    for (int ks = 0; ks < K; ks += 32) {
        bf16x8 a = *(const bf16x8*)(ap + ks);
        bf16x8 b = *(const bf16x8*)(bp + ks);
        acc = __builtin_amdgcn_mfma_f32_16x16x32_bf16(a, b, acc, 0, 0, 0);
    }
    // C/D layout (m89-verified): col = lane&15, row = quad*4 + reg
    for (int r = 0; r < 4; ++r) {
        size_t row = (size_t)(m0 + quad * 4 + r);
        int col = n0 + lm;
        if (Cf) Cf[row * N + col] = acc[r];
        else    Cb[row * N + col] = (bf16)acc[r];
    }
}

// ---------- RoPE (interleaved pairs, reference convention) ----------
// q_lin: (B,S,H*64) bf16;  k_lin: (B,S,KVH*64) bf16
// Qr: (B,H,S,64) bf16;     Kr: (B,KVH,S,64) bf16
__global__ void rope_kernel(const bf16* __restrict__ q_lin, const bf16* __restrict__ k_lin,
                            const float* __restrict__ cosb, const float* __restrict__ sinb,
                            bf16* __restrict__ Qr, bf16* __restrict__ Kr) {
    int tid = blockIdx.x * blockDim.x + threadIdx.x;
    const int total = BB * SS * (NH + NKVH) * 32;
    if (tid >= total) return;
    int i  = tid & 31;
    int hh = (tid >> 5) % (NH + NKVH);
    int bs = tid / (32 * (NH + NKVH));
    int b = bs / SS, s = bs - b * SS;
    float c  = cosb[(size_t)bs * 32 + i];
    float sn = sinb[(size_t)bs * 32 + i];
    if (hh < NH) {
        const bf16* src = q_lin + (size_t)bs * DD + hh * HD + 2 * i;
        float x1 = (float)src[0], x2 = (float)src[1];
        bf16* dst = Qr + ((size_t)(b * NH + hh) * SS + s) * HD + 2 * i;
        dst[0] = (bf16)(x1 * c - x2 * sn);
        dst[1] = (bf16)(x1 * sn + x2 * c);
    } else {
        int kvh = hh - NH;
        const bf16* src = k_lin + (size_t)bs * (NKVH * HD) + kvh * HD + 2 * i;
        float x1 = (float)src[0], x2 = (float)src[1];
        bf16* dst = Kr + ((size_t)(b * NKVH + kvh) * SS + s) * HD + 2 * i;
        dst[0] = (bf16)(x1 * c - x2 * sn);
        dst[1] = (bf16)(x1 * sn + x2 * c);
    }
}

// v_lin (B,S,KVH*64) -> Vt (B,KVH,64,S)  (d-major so PV B-fragments are contiguous)
__global__ void scatter_v_kernel(const bf16* __restrict__ v_lin, bf16* __restrict__ Vt) {
    int tid = blockIdx.x * blockDim.x + threadIdx.x;
    const int total = BB * SS * NKVH * HD;
    if (tid >= total) return;
    int d   = tid & 63;
    int kvh = (tid >> 6) & 3;
    int bs  = tid >> 8;
    int b = bs / SS, s = bs - b * SS;
    Vt[((size_t)(b * NKVH + kvh) * HD + d) * SS + s] = v_lin[tid];
}

// ---------- flash attention: 1 wave per (b, h, 16-query tile) ----------
__global__ __launch_bounds__(64) void attn_kernel(const bf16* __restrict__ Qr,
                                                  const bf16* __restrict__ Kr,
                                                  const bf16* __restrict__ Vt,
                                                  bf16* __restrict__ ctx) {
    const int NQT = SS / 16;
    int lane = threadIdx.x;
    int lm = lane & 15, quad = lane >> 4;
    int bid = blockIdx.x;                // (b*NH + h)*NQT + qt
    int qt = bid % NQT;
    int bh = bid / NQT;
    int h = bh % NH;
    int b = bh / NH;
    int kvh = h / GRP;
    int q0 = qt * 16;

    const bf16* qbase = Qr + ((size_t)(b * NH + h) * SS + q0 + lm) * HD + quad * 8;
    bf16x8 qlo = *(const bf16x8*)(qbase);
    bf16x8 qhi = *(const bf16x8*)(qbase + 32);

    const bf16* kbase  = Kr + (size_t)(b * NKVH + kvh) * SS * HD;
    const bf16* vtbase = Vt + (size_t)(b * NKVH + kvh) * HD * SS;

    __shared__ __align__(16) bf16 p_lds[16][32];

    float m_old[4], l_old[4];
    floatx4 o_acc[4];
    for (int r = 0; r < 4; ++r) { m_old[r] = -1e30f; l_old[r] = 0.f; }
    for (int dt = 0; dt < 4; ++dt) o_acc[dt] = floatx4{0.f, 0.f, 0.f, 0.f};

    int kend = q0 + 16;                  // exclusive causal bound
    for (int kb = 0; kb < kend; kb += 32) {
        // ---- S = Q K^T for two 16-key tiles ----
        floatx4 s_acc[2];
        for (int t = 0; t < 2; ++t) {
            const bf16* kp = kbase + (size_t)(kb + t * 16 + lm) * HD + quad * 8;
            bf16x8 klo = *(const bf16x8*)kp;
            bf16x8 khi = *(const bf16x8*)(kp + 32);
            floatx4 sa = {0.f, 0.f, 0.f, 0.f};
            sa = __builtin_amdgcn_mfma_f32_16x16x32_bf16(qlo, klo, sa, 0, 0, 0);
            sa = __builtin_amdgcn_mfma_f32_16x16x32_bf16(qhi, khi, sa, 0, 0, 0);
            s_acc[t] = sa;
        }
        // ---- scale + causal mask + per-row block max (rows = quad*4+r) ----
        float sc[2][4], mblk[4];
        for (int r = 0; r < 4; ++r) {
            int qi = q0 + quad * 4 + r;
            float s0 = s_acc[0][r] * SCALE + ((kb + lm)      > qi ? NEGBIG : 0.f);
            float s1 = s_acc[1][r] * SCALE + ((kb + 16 + lm) > qi ? NEGBIG : 0.f);
            sc[0][r] = s0; sc[1][r] = s1;
            float mx = fmaxf(s0, s1);
            for (int d = 1; d < 16; d <<= 1) mx = fmaxf(mx, __shfl_xor(mx, d));
            mblk[r] = mx;
        }
        __syncthreads();   // protect p_lds from previous iteration's reads
        for (int r = 0; r < 4; ++r) {
            float m_new = fmaxf(m_old[r], mblk[r]);
            float alpha = __expf(m_old[r] - m_new);
            float p0 = __expf(sc[0][r] - m_new);
            float p1 = __expf(sc[1][r] - m_new);
            float ls = p0 + p1;
            for (int d = 1; d < 16; d <<= 1) ls += __shfl_xor(ls, d);
            l_old[r] = l_old[r] * alpha + ls;
            m_old[r] = m_new;
            for (int dt = 0; dt < 4; ++dt) o_acc[dt][r] *= alpha;
            p_lds[quad * 4 + r][lm]      = (bf16)p0;
            p_lds[quad * 4 + r][16 + lm] = (bf16)p1;
        }
        __syncthreads();
        // ---- O += P V  (P via LDS C->A layout transform; Vt gives contiguous B-frag) ----
        bf16x8 pf = *(const bf16x8*)&p_lds[lm][quad * 8];
        for (int dt = 0; dt < 4; ++dt) {
            const bf16* vp = vtbase + (size_t)(dt * 16 + lm) * SS + kb + quad * 8;
            bf16x8 vf = *(const bf16x8*)vp;
            o_acc[dt] = __builtin_amdgcn_mfma_f32_16x16x32_bf16(pf, vf, o_acc[dt], 0, 0, 0);
        }
    }
    // ---- epilogue: ctx[b, s, h*64 + d] = O / l ----
    for (int r = 0; r < 4; ++r) {
        int qi = q0 + quad * 4 + r;
        float inv = 1.f / l_old[r];
        for (int dt = 0; dt < 4; ++dt) {
            ctx[((size_t)b * SS + qi) * DD + h * HD + dt * 16 + lm] =
                (bf16)(o_acc[dt][r] * inv);
        }
    }
}

// ---------- host ----------
extern "C" void kernel_launch(void* const* d_in, const int* in_sizes, int n_in,
                              void* d_out, int out_size, void* d_ws, size_t ws_size,
                              hipStream_t stream) {
    const float* hs   = (const float*)d_in[0];
    const float* cosb = (const float*)d_in[1];
    const float* sinb = (const float*)d_in[2];
    // d_in[3] = attention_mask (pure causal; recomputed in-kernel)
    const float* Wq = (const float*)d_in[4];
    const float* Wk = (const float*)d_in[5];
    const float* Wv = (const float*)d_in[6];
    const float* Wo = (const float*)d_in[7];
    float* out = (float*)d_out;

    char* ws = (char*)d_ws;
    size_t off = 0;
    auto alloc = [&](size_t bytes) {
        char* p = ws + off;
        off += (bytes + 255) & ~(size_t)255;
        return p;
    };
    const size_t MT = (size_t)BB * SS;        // 4096 tokens
    bf16* hsb   = (bf16*)alloc(MT * DD * 2);              // 8 MB
    bf16* WqT   = (bf16*)alloc((size_t)DD * DD * 2);      // 2 MB
    bf16* WkT   = (bf16*)alloc((size_t)256 * DD * 2);     // 0.5 MB
    bf16* WvT   = (bf16*)alloc((size_t)256 * DD * 2);     // 0.5 MB
    bf16* WoT   = (bf16*)alloc((size_t)DD * DD * 2);      // 2 MB
    bf16* q_lin = (bf16*)alloc(MT * DD * 2);              // 8 MB
    bf16* k_lin = (bf16*)alloc(MT * 256 * 2);             // 2 MB
    bf16* v_lin = (bf16*)alloc(MT * 256 * 2);             // 2 MB
    bf16* Qr    = (bf16*)alloc(MT * DD * 2);              // 8 MB
    bf16* Kr    = (bf16*)alloc(MT * 256 * 2);             // 2 MB
    bf16* Vt    = (bf16*)alloc(MT * 256 * 2);             // 2 MB
    bf16* ctx   = (bf16*)alloc(MT * DD * 2);              // 8 MB  (total ~45 MB)

    // 1. casts / transposes
    {
        int n = (int)(MT * DD);
        cast_bf16_kernel<<<(n + 255) / 256, 256, 0, stream>>>(hs, hsb, n);
        transpose_cast_kernel<<<(DD * DD + 255) / 256, 256, 0, stream>>>(Wq, WqT, DD, DD);
        transpose_cast_kernel<<<(DD * 256 + 255) / 256, 256, 0, stream>>>(Wk, WkT, DD, 256);
        transpose_cast_kernel<<<(DD * 256 + 255) / 256, 256, 0, stream>>>(Wv, WvT, DD, 256);
        transpose_cast_kernel<<<(DD * DD + 255) / 256, 256, 0, stream>>>(Wo, WoT, DD, DD);
    }
    // 2. QKV projections
    gemm_bt<<<dim3(MT / 16, DD / 64), 256, 0, stream>>>(hsb, WqT, q_lin, nullptr,
                                                        (int)MT, DD, DD);
    gemm_bt<<<dim3(MT / 16, 256 / 64), 256, 0, stream>>>(hsb, WkT, k_lin, nullptr,
                                                         (int)MT, 256, DD);
    gemm_bt<<<dim3(MT / 16, 256 / 64), 256, 0, stream>>>(hsb, WvT, v_lin, nullptr,
                                                         (int)MT, 256, DD);
    // 3. RoPE + V scatter
    {
        int n = BB * SS * (NH + NKVH) * 32;
        rope_kernel<<<(n + 255) / 256, 256, 0, stream>>>(q_lin, k_lin, cosb, sinb, Qr, Kr);
        int nv = BB * SS * NKVH * HD;
        scatter_v_kernel<<<(nv + 255) / 256, 256, 0, stream>>>(v_lin, Vt);
    }
    // 4. attention
    attn_kernel<<<BB * NH * (SS / 16), 64, 0, stream>>>(Qr, Kr, Vt, ctx);
    // 5. output projection (fp32 out)
    gemm_bt<<<dim3(MT / 16, DD / 64), 256, 0, stream>>>(ctx, WoT, nullptr, out,
                                                        (int)MT, DD, DD);

    (void)in_sizes; (void)n_in; (void)out_size; (void)ws_size;
}

// Round 2
// 408.663 us; speedup vs baseline: 1.6203x; 1.6203x over previous
//
#include <hip/hip_runtime.h>

#define BB 2
#define SS 2048
#define DD 1024
#define NH 16
#define NKVH 4
#define GRP 4
#define HD 64
#define QKVN 1536          // fused Wqkv output columns: 1024 q | 256 k | 256 v
#define SCALE 0.125f       // 64^-0.5
typedef __bf16 bf16;
typedef __bf16 bf16x4 __attribute__((ext_vector_type(4)));
typedef __bf16 bf16x8 __attribute__((ext_vector_type(8)));
typedef float floatx4 __attribute__((ext_vector_type(4)));

#define ASYNC16(gp, lp) __builtin_amdgcn_global_load_lds(                      \
    (const __attribute__((address_space(1))) unsigned int*)(gp),               \
    (__attribute__((address_space(3))) unsigned int*)(lp), 16, 0, 0)

// ---------- prep ----------
__global__ void cast_bf16x4_kernel(const float4* __restrict__ x, bf16x4* __restrict__ y, int n4) {
    int i = blockIdx.x * blockDim.x + threadIdx.x;
    if (i >= n4) return;
    float4 v = x[i];
    y[i] = bf16x4{(bf16)v.x, (bf16)v.y, (bf16)v.z, (bf16)v.w};
}

// dst[n][k] = W[k][n]  (W is K x N row-major fp32), dst rows have stride K
__global__ void transpose_cast_kernel(const float* __restrict__ W, bf16* __restrict__ dst,
                                      int K, int N) {
    int i = blockIdx.x * blockDim.x + threadIdx.x;
    if (i >= K * N) return;
    int k = i / N, n = i - k * N;
    dst[(size_t)n * K + k] = (bf16)W[i];
}

// ---------- m97-style GEMM: C[M,N] = A[M,K] * Bt[N,K]^T ----------
// 128x128 tile, BK=32, 256 threads (4 waves), global_load_lds width-16 staging.
__global__ __launch_bounds__(256) void gemm128(const bf16* __restrict__ A,
                                               const bf16* __restrict__ Bt,
                                               bf16* __restrict__ Cb,
                                               float* __restrict__ Cf,
                                               int M, int N, int K) {
    __shared__ bf16 As[128 * 32];
    __shared__ bf16 Bs[128 * 32];
    int t = threadIdx.x;
    int wave = t >> 6, lane = t & 63;
    int lm = lane & 15, quad = lane >> 4;
    int m0 = blockIdx.x * 128, n0 = blockIdx.y * 128;
    int wr = wave >> 1, wc = wave & 1;

    int srow = t >> 2;             // 0..63
    int scol = (t & 3) * 8;        // 0,8,16,24
    const bf16* ga = A  + (size_t)(m0 + srow) * K + scol;
    const bf16* gb = Bt + (size_t)(n0 + srow) * K + scol;
    bf16* la0 = &As[wave * 512];
    bf16* lb0 = &Bs[wave * 512];

    floatx4 acc[4][4];
    for (int i = 0; i < 4; ++i)
        for (int j = 0; j < 4; ++j) acc[i][j] = floatx4{0.f, 0.f, 0.f, 0.f};

    for (int ks = 0; ks < K; ks += 32) {
        __syncthreads();
        ASYNC16(ga + ks,                la0);
        ASYNC16(ga + ks + (size_t)64*K, la0 + 2048);
        ASYNC16(gb + ks,                lb0);
        ASYNC16(gb + ks + (size_t)64*K, lb0 + 2048);
        __syncthreads();   // drains vmcnt before barrier
        bf16x8 af[4], bfr[4];
        for (int mi = 0; mi < 4; ++mi)
            af[mi] = *(const bf16x8*)&As[(wr * 64 + mi * 16 + lm) * 32 + quad * 8];
        for (int ni = 0; ni < 4; ++ni)
            bfr[ni] = *(const bf16x8*)&Bs[(wc * 64 + ni * 16 + lm) * 32 + quad * 8];
        for (int mi = 0; mi < 4; ++mi)
            for (int ni = 0; ni < 4; ++ni)
                acc[mi][ni] = __builtin_amdgcn_mfma_f32_16x16x32_bf16(af[mi], bfr[ni],
                                                                      acc[mi][ni], 0, 0, 0);
    }
    for (int mi = 0; mi < 4; ++mi)
        for (int ni = 0; ni < 4; ++ni)
            for (int r = 0; r < 4; ++r) {
                size_t row = (size_t)(m0 + wr * 64 + mi * 16 + quad * 4 + r);
                int col = n0 + wc * 64 + ni * 16 + lm;
                if (Cf) Cf[row * N + col] = acc[mi][ni][r];
                else    Cb[row * N + col] = (bf16)acc[mi][ni][r];
            }
}

// ---------- RoPE from fused qkv_lin (stride QKVN) ----------
__global__ void rope_kernel(const bf16* __restrict__ qkv,
                            const float* __restrict__ cosb, const float* __restrict__ sinb,
                            bf16* __restrict__ Qr, bf16* __restrict__ Kr) {
    int tid = blockIdx.x * blockDim.x + threadIdx.x;
    const int total = BB * SS * (NH + NKVH) * 32;
    if (tid >= total) return;
    int i  = tid & 31;
    int hh = (tid >> 5) % (NH + NKVH);
    int bs = tid / (32 * (NH + NKVH));
    int b = bs / SS, s = bs - b * SS;
    float c  = cosb[(size_t)bs * 32 + i];
    float sn = sinb[(size_t)bs * 32 + i];
    if (hh < NH) {
        const bf16* src = qkv + (size_t)bs * QKVN + hh * HD + 2 * i;
        float x1 = (float)src[0], x2 = (float)src[1];
        bf16* dst = Qr + ((size_t)(b * NH + hh) * SS + s) * HD + 2 * i;
        dst[0] = (bf16)(x1 * c - x2 * sn);
        dst[1] = (bf16)(x1 * sn + x2 * c);
    } else {
        int kvh = hh - NH;
        const bf16* src = qkv + (size_t)bs * QKVN + 1024 + kvh * HD + 2 * i;
        float x1 = (float)src[0], x2 = (float)src[1];
        bf16* dst = Kr + ((size_t)(b * NKVH + kvh) * SS + s) * HD + 2 * i;
        dst[0] = (bf16)(x1 * c - x2 * sn);
        dst[1] = (bf16)(x1 * sn + x2 * c);
    }
}

// qkv v-columns -> Vt (B,KVH,64,S)
__global__ void scatter_v_kernel(const bf16* __restrict__ qkv, bf16* __restrict__ Vt) {
    int tid = blockIdx.x * blockDim.x + threadIdx.x;
    const int total = BB * SS * NKVH * HD;
    if (tid >= total) return;
    int d   = tid & 63;
    int kvh = (tid >> 6) & 3;
    int bs  = tid >> 8;
    int b = bs / SS, s = bs - b * SS;
    Vt[((size_t)(b * NKVH + kvh) * HD + d) * SS + s] =
        qkv[(size_t)bs * QKVN + 1280 + kvh * HD + d];
}

// ---------- flash attention, transposed scores ----------
// 1 wave / (b,h,16-query tile); 64-key chunks; S^T = K·Q^T so softmax reduction
// is a 15-op register fold + 2 quad shuffles per chunk.
__global__ __launch_bounds__(64) void attn_kernel(const bf16* __restrict__ Qr,
                                                  const bf16* __restrict__ Kr,
                                                  const bf16* __restrict__ Vt,
                                                  bf16* __restrict__ ctx) {
    __shared__ __align__(16) bf16 p_lds[16][72];   // [query][key], +8 pad -> 2-way max
    __shared__ float bcast[16];
    const int NQT = SS / 16;
    int lane = threadIdx.x;
    int lm = lane & 15, quad = lane >> 4;
    int bid = blockIdx.x;
    int qt = (NQT - 1) - (bid & (NQT - 1));   // longest q-tiles dispatch first
    int bh = bid >> 7;
    int h = bh & (NH - 1), b = bh >> 4;
    int kvh = h >> 2;
    int q0 = qt * 16;

    const bf16* qb = Qr + ((size_t)(b * NH + h) * SS + q0 + lm) * HD;
    bf16x8 qf0 = *(const bf16x8*)(qb + quad * 8);
    bf16x8 qf1 = *(const bf16x8*)(qb + 32 + quad * 8);
    const bf16* kbase = Kr + (size_t)(b * NKVH + kvh) * SS * HD;
    const bf16* vbase = Vt + (size_t)(b * NKVH + kvh) * HD * SS;

    float m_prev = -1e30f, l_prev = 0.f;
    floatx4 o[4];
    for (int dt = 0; dt < 4; ++dt) o[dt] = floatx4{0.f, 0.f, 0.f, 0.f};

    int kend = q0 + 16;
    int nch = (kend + 63) >> 6;
    for (int ck = 0; ck < nch; ++ck) {
        int kb = ck * 64;
        // S^T: rows = keys, cols = queries
        floatx4 st[4];
        for (int tt = 0; tt < 4; ++tt) {
            const bf16* kp = kbase + (size_t)(kb + tt * 16 + lm) * HD + quad * 8;
            bf16x8 k0 = *(const bf16x8*)kp;
            bf16x8 k1 = *(const bf16x8*)(kp + 32);
            floatx4 s = {0.f, 0.f, 0.f, 0.f};
            s = __builtin_amdgcn_mfma_f32_16x16x32_bf16(k0, qf0, s, 0, 0, 0);
            s = __builtin_amdgcn_mfma_f32_16x16x32_bf16(k1, qf1, s, 0, 0, 0);
            st[tt] = s;
        }
        bool needmask = (kb + 63 > q0);
        float mx = -1e30f;
        for (int tt = 0; tt < 4; ++tt)
            for (int r = 0; r < 4; ++r) {
                float v = st[tt][r] * SCALE;
                if (needmask && (kb + tt * 16 + quad * 4 + r > q0 + lm)) v = -1e30f;
                st[tt][r] = v;
                mx = fmaxf(mx, v);
            }
        mx = fmaxf(mx, __shfl_xor(mx, 16));
        mx = fmaxf(mx, __shfl_xor(mx, 32));
        float m_new = fmaxf(m_prev, mx);
        float alpha = __expf(m_prev - m_new);
        m_prev = m_new;
        float ls = 0.f;
        for (int tt = 0; tt < 4; ++tt)
            for (int r = 0; r < 4; ++r) {
                float p = __expf(st[tt][r] - m_new);
                st[tt][r] = p;
                ls += p;
            }
        ls += __shfl_xor(ls, 16);
        ls += __shfl_xor(ls, 32);
        l_prev = l_prev * alpha + ls;

        __syncthreads();   // previous iter's P reads complete
        if (quad == 0) bcast[lm] = alpha;
        for (int tt = 0; tt < 4; ++tt) {
            bf16x4 pk = {(bf16)st[tt][0], (bf16)st[tt][1], (bf16)st[tt][2], (bf16)st[tt][3]};
            *(bf16x4*)&p_lds[lm][tt * 16 + quad * 4] = pk;
        }
        __syncthreads();
        // rescale O (rows = query = quad*4+r) by alpha broadcast
        for (int r = 0; r < 4; ++r) {
            float a = bcast[quad * 4 + r];
            for (int dt = 0; dt < 4; ++dt) o[dt][r] *= a;
        }
        // O += P V
        bf16x8 pa0 = *(const bf16x8*)&p_lds[lm][quad * 8];
        bf16x8 pa1 = *(const bf16x8*)&p_lds[lm][32 + quad * 8];
        for (int dt = 0; dt < 4; ++dt) {
            const bf16* vp = vbase + (size_t)(dt * 16 + lm) * SS + kb;
            bf16x8 v0 = *(const bf16x8*)(vp + quad * 8);
            bf16x8 v1 = *(const bf16x8*)(vp + 32 + quad * 8);
            o[dt] = __builtin_amdgcn_mfma_f32_16x16x32_bf16(pa0, v0, o[dt], 0, 0, 0);
            o[dt] = __builtin_amdgcn_mfma_f32_16x16x32_bf16(pa1, v1, o[dt], 0, 0, 0);
        }
    }
    __syncthreads();
    if (quad == 0) bcast[lm] = 1.f / l_prev;
    __syncthreads();
    for (int r = 0; r < 4; ++r) {
        float inv = bcast[quad * 4 + r];
        int qi = q0 + quad * 4 + r;
        for (int dt = 0; dt < 4; ++dt)
            ctx[((size_t)b * SS + qi) * DD + h * HD + dt * 16 + lm] =
                (bf16)(o[dt][r] * inv);
    }
}

// ---------- host ----------
extern "C" void kernel_launch(void* const* d_in, const int* in_sizes, int n_in,
                              void* d_out, int out_size, void* d_ws, size_t ws_size,
                              hipStream_t stream) {
    const float* hs   = (const float*)d_in[0];
    const float* cosb = (const float*)d_in[1];
    const float* sinb = (const float*)d_in[2];
    const float* Wq = (const float*)d_in[4];
    const float* Wk = (const float*)d_in[5];
    const float* Wv = (const float*)d_in[6];
    const float* Wo = (const float*)d_in[7];
    float* out = (float*)d_out;

    char* ws = (char*)d_ws;
    size_t off = 0;
    auto alloc = [&](size_t bytes) {
        char* p = ws + off;
        off += (bytes + 255) & ~(size_t)255;
        return p;
    };
    const size_t MT = (size_t)BB * SS;                    // 4096 tokens
    bf16* hsb     = (bf16*)alloc(MT * DD * 2);            // 8 MB
    bf16* WqkvT   = (bf16*)alloc((size_t)QKVN * DD * 2);  // 3 MB  rows: q|k|v
    bf16* WoT     = (bf16*)alloc((size_t)DD * DD * 2);    // 2 MB
    bf16* qkv_lin = (bf16*)alloc(MT * QKVN * 2);          // 12 MB
    bf16* Qr      = (bf16*)alloc(MT * DD * 2);            // 8 MB
    bf16* Kr      = (bf16*)alloc(MT * 256 * 2);           // 2 MB
    bf16* Vt      = (bf16*)alloc(MT * 256 * 2);           // 2 MB
    bf16* ctx     = (bf16*)alloc(MT * DD * 2);            // 8 MB

    // 1. casts / transposes
    {
        int n4 = (int)(MT * DD / 4);
        cast_bf16x4_kernel<<<(n4 + 255) / 256, 256, 0, stream>>>((const float4*)hs,
                                                                 (bf16x4*)hsb, n4);
        transpose_cast_kernel<<<(DD * DD + 255) / 256, 256, 0, stream>>>(Wq, WqkvT, DD, DD);
        transpose_cast_kernel<<<(DD * 256 + 255) / 256, 256, 0, stream>>>(Wk, WqkvT + (size_t)1024 * DD, DD, 256);
        transpose_cast_kernel<<<(DD * 256 + 255) / 256, 256, 0, stream>>>(Wv, WqkvT + (size_t)1280 * DD, DD, 256);
        transpose_cast_kernel<<<(DD * DD + 255) / 256, 256, 0, stream>>>(Wo, WoT, DD, DD);
    }
    // 2. fused QKV projection: (4096 x 1536) = hsb (4096x1024) * WqkvT^T
    gemm128<<<dim3(MT / 128, QKVN / 128), 256, 0, stream>>>(hsb, WqkvT, qkv_lin, nullptr,
                                                            (int)MT, QKVN, DD);
    // 3. RoPE + V scatter
    {
        int n = BB * SS * (NH + NKVH) * 32;
        rope_kernel<<<(n + 255) / 256, 256, 0, stream>>>(qkv_lin, cosb, sinb, Qr, Kr);
        int nv = BB * SS * NKVH * HD;
        scatter_v_kernel<<<(nv + 255) / 256, 256, 0, stream>>>(qkv_lin, Vt);
    }
    // 4. attention
    attn_kernel<<<BB * NH * (SS / 16), 64, 0, stream>>>(Qr, Kr, Vt, ctx);
    // 5. output projection (fp32 out)
    gemm128<<<dim3(MT / 128, DD / 128), 256, 0, stream>>>(ctx, WoT, nullptr, out,
                                                          (int)MT, DD, DD);

    (void)in_sizes; (void)n_in; (void)out_size; (void)ws_size;
}

// Round 3
// 228.547 us; speedup vs baseline: 2.8972x; 1.7881x over previous
//
#include <hip/hip_runtime.h>

#define BB 2
#define SS 2048
#define DD 1024
#define NH 16
#define NKVH 4
#define GRP 4
#define HD 64
#define QKVN 1536          // fused Wqkv output columns: 1024 q | 256 k | 256 v
#define SCALE 0.125f       // 64^-0.5
typedef __bf16 bf16;
typedef __bf16 bf16x4 __attribute__((ext_vector_type(4)));
typedef __bf16 bf16x8 __attribute__((ext_vector_type(8)));
typedef float floatx4 __attribute__((ext_vector_type(4)));

#define ASYNC16(gp, lp) __builtin_amdgcn_global_load_lds(                      \
    (const __attribute__((address_space(1))) unsigned int*)(gp),               \
    (__attribute__((address_space(3))) unsigned int*)(lp), 16, 0, 0)

// ---------- prep ----------
__global__ void cast_bf16x4_kernel(const float4* __restrict__ x, bf16x4* __restrict__ y, int n4) {
    int i = blockIdx.x * blockDim.x + threadIdx.x;
    if (i >= n4) return;
    float4 v = x[i];
    y[i] = bf16x4{(bf16)v.x, (bf16)v.y, (bf16)v.z, (bf16)v.w};
}

// all four weight transposes in one launch
__global__ void prep_weights(const float* __restrict__ Wq, const float* __restrict__ Wk,
                             const float* __restrict__ Wv, const float* __restrict__ Wo,
                             bf16* __restrict__ WqkvT, bf16* __restrict__ WoT) {
    int i = blockIdx.x * blockDim.x + threadIdx.x;
    const int NQKV = DD * QKVN;
    if (i < NQKV) {
        int k = i / QKVN, n = i - k * QKVN;
        float v = (n < 1024) ? Wq[(size_t)k * 1024 + n]
                : (n < 1280) ? Wk[(size_t)k * 256 + (n - 1024)]
                             : Wv[(size_t)k * 256 + (n - 1280)];
        WqkvT[(size_t)n * DD + k] = (bf16)v;
    } else {
        int j = i - NQKV;
        if (j < DD * DD) {
            int k = j / DD, n = j - k * DD;
            WoT[(size_t)n * DD + k] = (bf16)Wo[j];
        }
    }
}

// ---------- m97-style GEMM: C[M,N] = A[M,K] * Bt[N,K]^T ----------
__global__ __launch_bounds__(256) void gemm128(const bf16* __restrict__ A,
                                               const bf16* __restrict__ Bt,
                                               bf16* __restrict__ Cb,
                                               float* __restrict__ Cf,
                                               int M, int N, int K) {
    __shared__ bf16 As[128 * 32];
    __shared__ bf16 Bs[128 * 32];
    int t = threadIdx.x;
    int wave = t >> 6, lane = t & 63;
    int lm = lane & 15, quad = lane >> 4;
    int m0 = blockIdx.x * 128, n0 = blockIdx.y * 128;
    int wr = wave >> 1, wc = wave & 1;

    int srow = t >> 2;
    int scol = (t & 3) * 8;
    const bf16* ga = A  + (size_t)(m0 + srow) * K + scol;
    const bf16* gb = Bt + (size_t)(n0 + srow) * K + scol;
    bf16* la0 = &As[wave * 512];
    bf16* lb0 = &Bs[wave * 512];

    floatx4 acc[4][4];
    for (int i = 0; i < 4; ++i)
        for (int j = 0; j < 4; ++j) acc[i][j] = floatx4{0.f, 0.f, 0.f, 0.f};

    for (int ks = 0; ks < K; ks += 32) {
        __syncthreads();
        ASYNC16(ga + ks,                la0);
        ASYNC16(ga + ks + (size_t)64*K, la0 + 2048);
        ASYNC16(gb + ks,                lb0);
        ASYNC16(gb + ks + (size_t)64*K, lb0 + 2048);
        __syncthreads();
        bf16x8 af[4], bfr[4];
        for (int mi = 0; mi < 4; ++mi)
            af[mi] = *(const bf16x8*)&As[(wr * 64 + mi * 16 + lm) * 32 + quad * 8];
        for (int ni = 0; ni < 4; ++ni)
            bfr[ni] = *(const bf16x8*)&Bs[(wc * 64 + ni * 16 + lm) * 32 + quad * 8];
        for (int mi = 0; mi < 4; ++mi)
            for (int ni = 0; ni < 4; ++ni)
                acc[mi][ni] = __builtin_amdgcn_mfma_f32_16x16x32_bf16(af[mi], bfr[ni],
                                                                      acc[mi][ni], 0, 0, 0);
    }
    for (int mi = 0; mi < 4; ++mi)
        for (int ni = 0; ni < 4; ++ni)
            for (int r = 0; r < 4; ++r) {
                size_t row = (size_t)(m0 + wr * 64 + mi * 16 + quad * 4 + r);
                int col = n0 + wc * 64 + ni * 16 + lm;
                if (Cf) Cf[row * N + col] = acc[mi][ni][r];
                else    Cb[row * N + col] = (bf16)acc[mi][ni][r];
            }
}

// ---------- RoPE from fused qkv_lin ----------
__global__ void rope_kernel(const bf16* __restrict__ qkv,
                            const float* __restrict__ cosb, const float* __restrict__ sinb,
                            bf16* __restrict__ Qr, bf16* __restrict__ Kr) {
    int tid = blockIdx.x * blockDim.x + threadIdx.x;
    const int total = BB * SS * (NH + NKVH) * 32;
    if (tid >= total) return;
    int i  = tid & 31;
    int hh = (tid >> 5) % (NH + NKVH);
    int bs = tid / (32 * (NH + NKVH));
    int b = bs / SS, s = bs - b * SS;
    float c  = cosb[(size_t)bs * 32 + i];
    float sn = sinb[(size_t)bs * 32 + i];
    if (hh < NH) {
        const bf16* src = qkv + (size_t)bs * QKVN + hh * HD + 2 * i;
        float x1 = (float)src[0], x2 = (float)src[1];
        bf16* dst = Qr + ((size_t)(b * NH + hh) * SS + s) * HD + 2 * i;
        dst[0] = (bf16)(x1 * c - x2 * sn);
        dst[1] = (bf16)(x1 * sn + x2 * c);
    } else {
        int kvh = hh - NH;
        const bf16* src = qkv + (size_t)bs * QKVN + 1024 + kvh * HD + 2 * i;
        float x1 = (float)src[0], x2 = (float)src[1];
        bf16* dst = Kr + ((size_t)(b * NKVH + kvh) * SS + s) * HD + 2 * i;
        dst[0] = (bf16)(x1 * c - x2 * sn);
        dst[1] = (bf16)(x1 * sn + x2 * c);
    }
}

// qkv v-columns -> Vt (B,KVH,64,S)
__global__ void scatter_v_kernel(const bf16* __restrict__ qkv, bf16* __restrict__ Vt) {
    int tid = blockIdx.x * blockDim.x + threadIdx.x;
    const int total = BB * SS * NKVH * HD;
    if (tid >= total) return;
    int d   = tid & 63;
    int kvh = (tid >> 6) & 3;
    int bs  = tid >> 8;
    int b = bs / SS, s = bs - b * SS;
    Vt[((size_t)(b * NKVH + kvh) * HD + d) * SS + s] =
        qkv[(size_t)bs * QKVN + 1280 + kvh * HD + d];
}

// ---------- flash attention: 4 waves / 64 queries per WG, LDS-staged K/V ----------
// Transposed scores S^T = K·Q^T. K/V chunk (64 keys) staged once per WG via
// global_load_lds with XOR swizzle (col16 ^= row&7, since async-LDS forbids pads).
// P transform + broadcasts are wave-private -> only 2 barriers per chunk.
__global__ __launch_bounds__(256, 4) void attn_kernel(const bf16* __restrict__ Qr,
                                                      const bf16* __restrict__ Kr,
                                                      const bf16* __restrict__ Vt,
                                                      bf16* __restrict__ ctx) {
    __shared__ __align__(16) bf16 kv[8192];          // K: [0,4096) V: [4096,8192) bf16
    __shared__ __align__(16) bf16 p_lds[4][16][72];  // per-wave P (stride 72)
    int t = threadIdx.x;
    int wave = t >> 6, lane = t & 63;
    int lm = lane & 15, quad = lane >> 4;
    int bid = blockIdx.x;
    int bh = bid & 31;                 // 2*16 head combos
    int h = bh & (NH - 1), b = bh >> 4;
    int qb = 31 - (bid >> 5);          // longest WGs dispatch first
    int kvh = h >> 2;
    int q0 = qb * 64;
    int q0w = q0 + wave * 16;

    const bf16* qp = Qr + ((size_t)(b * NH + h) * SS + q0w + lm) * HD;
    bf16x8 qf0 = *(const bf16x8*)(qp + quad * 8);
    bf16x8 qf1 = *(const bf16x8*)(qp + 32 + quad * 8);
    const bf16* kbase = Kr + (size_t)(b * NKVH + kvh) * SS * HD;
    const bf16* vbase = Vt + (size_t)(b * NKVH + kvh) * HD * SS;

    // staging addresses: 8 threads per 64-elem row, 16B chunks XOR-permuted
    int srow = t >> 3;                       // 0..31
    int scol = ((t & 7) ^ (srow & 7)) * 8;
    const bf16* gk = kbase + (size_t)srow * HD + scol;   // + (kb + c*32)*HD
    const bf16* gv = vbase + (size_t)srow * SS + scol;   // + c*32*SS + kb
    bf16* lds_w = kv + wave * 512;                       // per-wave async dest base

    float m_prev = -1e30f, l_prev = 0.f;
    floatx4 o[4];
    for (int dt = 0; dt < 4; ++dt) o[dt] = floatx4{0.f, 0.f, 0.f, 0.f};

    int nch = qb + 1;
    for (int ck = 0; ck < nch; ++ck) {
        int kb = ck * 64;
        __syncthreads();                               // all waves done with prev K/V
        ASYNC16(gk + (size_t)kb * HD,          lds_w);
        ASYNC16(gk + (size_t)(kb + 32) * HD,   lds_w + 2048);
        ASYNC16(gv + kb,                       lds_w + 4096);
        ASYNC16(gv + (size_t)32 * SS + kb,     lds_w + 6144);
        __syncthreads();                               // staging complete

        // S^T = K·Q^T  (rows = keys, cols = queries)
        floatx4 st[4];
        for (int tt = 0; tt < 4; ++tt) {
            int kk = tt * 16 + lm;                     // kk&7 == lm&7
            const bf16* krow = kv + kk * 64;
            bf16x8 k0 = *(const bf16x8*)(krow + ((quad ^ (lm & 7)) * 8));
            bf16x8 k1 = *(const bf16x8*)(krow + (((quad + 4) ^ (lm & 7)) * 8));
            floatx4 s = {0.f, 0.f, 0.f, 0.f};
            s = __builtin_amdgcn_mfma_f32_16x16x32_bf16(k0, qf0, s, 0, 0, 0);
            s = __builtin_amdgcn_mfma_f32_16x16x32_bf16(k1, qf1, s, 0, 0, 0);
            st[tt] = s;
        }
        bool needmask = (ck == nch - 1);
        float mx = -1e30f;
        for (int tt = 0; tt < 4; ++tt)
            for (int r = 0; r < 4; ++r) {
                float v = st[tt][r] * SCALE;
                if (needmask && (kb + tt * 16 + quad * 4 + r > q0w + lm)) v = -1e30f;
                st[tt][r] = v;
                mx = fmaxf(mx, v);
            }
        mx = fmaxf(mx, __shfl_xor(mx, 16));
        mx = fmaxf(mx, __shfl_xor(mx, 32));
        float m_new = fmaxf(m_prev, mx);
        float alpha = __expf(m_prev - m_new);
        m_prev = m_new;
        float ls = 0.f;
        for (int tt = 0; tt < 4; ++tt)
            for (int r = 0; r < 4; ++r) {
                float p = __expf(st[tt][r] - m_new);
                st[tt][r] = p;
                ls += p;
            }
        ls += __shfl_xor(ls, 16);
        ls += __shfl_xor(ls, 32);
        l_prev = l_prev * alpha + ls;

        // P^T -> A-layout via wave-private LDS (no barrier needed)
        for (int tt = 0; tt < 4; ++tt) {
            bf16x4 pk = {(bf16)st[tt][0], (bf16)st[tt][1], (bf16)st[tt][2], (bf16)st[tt][3]};
            *(bf16x4*)&p_lds[wave][lm][tt * 16 + quad * 4] = pk;
        }
        // rescale O (row = query = quad*4+r) via shfl broadcast of alpha
        for (int r = 0; r < 4; ++r) {
            float a = __shfl(alpha, quad * 4 + r);
            for (int dt = 0; dt < 4; ++dt) o[dt][r] *= a;
        }
        // O += P V
        bf16x8 pa0 = *(const bf16x8*)&p_lds[wave][lm][quad * 8];
        bf16x8 pa1 = *(const bf16x8*)&p_lds[wave][lm][32 + quad * 8];
        for (int dt = 0; dt < 4; ++dt) {
            int d = dt * 16 + lm;                      // d&7 == lm&7
            const bf16* vrow = kv + 4096 + d * 64;
            bf16x8 v0 = *(const bf16x8*)(vrow + ((quad ^ (lm & 7)) * 8));
            bf16x8 v1 = *(const bf16x8*)(vrow + (((quad + 4) ^ (lm & 7)) * 8));
            o[dt] = __builtin_amdgcn_mfma_f32_16x16x32_bf16(pa0, v0, o[dt], 0, 0, 0);
            o[dt] = __builtin_amdgcn_mfma_f32_16x16x32_bf16(pa1, v1, o[dt], 0, 0, 0);
        }
    }
    float linv = 1.f / l_prev;
    for (int r = 0; r < 4; ++r) {
        float inv = __shfl(linv, quad * 4 + r);
        int qi = q0w + quad * 4 + r;
        for (int dt = 0; dt < 4; ++dt)
            ctx[((size_t)b * SS + qi) * DD + h * HD + dt * 16 + lm] =
                (bf16)(o[dt][r] * inv);
    }
}

// ---------- host ----------
extern "C" void kernel_launch(void* const* d_in, const int* in_sizes, int n_in,
                              void* d_out, int out_size, void* d_ws, size_t ws_size,
                              hipStream_t stream) {
    const float* hs   = (const float*)d_in[0];
    const float* cosb = (const float*)d_in[1];
    const float* sinb = (const float*)d_in[2];
    const float* Wq = (const float*)d_in[4];
    const float* Wk = (const float*)d_in[5];
    const float* Wv = (const float*)d_in[6];
    const float* Wo = (const float*)d_in[7];
    float* out = (float*)d_out;

    char* ws = (char*)d_ws;
    size_t off = 0;
    auto alloc = [&](size_t bytes) {
        char* p = ws + off;
        off += (bytes + 255) & ~(size_t)255;
        return p;
    };
    const size_t MT = (size_t)BB * SS;                    // 4096 tokens
    bf16* hsb     = (bf16*)alloc(MT * DD * 2);
    bf16* WqkvT   = (bf16*)alloc((size_t)QKVN * DD * 2);
    bf16* WoT     = (bf16*)alloc((size_t)DD * DD * 2);
    bf16* qkv_lin = (bf16*)alloc(MT * QKVN * 2);
    bf16* Qr      = (bf16*)alloc(MT * DD * 2);
    bf16* Kr      = (bf16*)alloc(MT * 256 * 2);
    bf16* Vt      = (bf16*)alloc(MT * 256 * 2);
    bf16* ctx     = (bf16*)alloc(MT * DD * 2);

    // 1. casts / transposes
    {
        int n4 = (int)(MT * DD / 4);
        cast_bf16x4_kernel<<<(n4 + 255) / 256, 256, 0, stream>>>((const float4*)hs,
                                                                 (bf16x4*)hsb, n4);
        int nw = DD * (QKVN + DD);
        prep_weights<<<(nw + 255) / 256, 256, 0, stream>>>(Wq, Wk, Wv, Wo, WqkvT, WoT);
    }
    // 2. fused QKV projection
    gemm128<<<dim3(MT / 128, QKVN / 128), 256, 0, stream>>>(hsb, WqkvT, qkv_lin, nullptr,
                                                            (int)MT, QKVN, DD);
    // 3. RoPE + V scatter
    {
        int n = BB * SS * (NH + NKVH) * 32;
        rope_kernel<<<(n + 255) / 256, 256, 0, stream>>>(qkv_lin, cosb, sinb, Qr, Kr);
        int nv = BB * SS * NKVH * HD;
        scatter_v_kernel<<<(nv + 255) / 256, 256, 0, stream>>>(qkv_lin, Vt);
    }
    // 4. attention: 1024 WGs (32 bh x 32 query-blocks), 4 waves each
    attn_kernel<<<1024, 256, 0, stream>>>(Qr, Kr, Vt, ctx);
    // 5. output projection (fp32 out)
    gemm128<<<dim3(MT / 128, DD / 128), 256, 0, stream>>>(ctx, WoT, nullptr, out,
                                                          (int)MT, DD, DD);

    (void)in_sizes; (void)n_in; (void)out_size; (void)ws_size;
}

// Round 4
// 210.852 us; speedup vs baseline: 3.1403x; 1.0839x over previous
//
#include <hip/hip_runtime.h>

#define BB 2
#define SS 2048
#define DD 1024
#define NH 16
#define NKVH 4
#define HD 64
#define QKVN 1536          // fused Wqkv output columns: 1024 q | 256 k | 256 v
#define SCALE 0.125f       // 64^-0.5
#define NITEMS 1024        // attn work items: 32 bh * 32 q-blocks

typedef __bf16 bf16;
typedef __bf16 bf16x4 __attribute__((ext_vector_type(4)));
typedef __bf16 bf16x8 __attribute__((ext_vector_type(8)));
typedef float floatx4 __attribute__((ext_vector_type(4)));

#define ASYNC16(gp, lp) __builtin_amdgcn_global_load_lds(                      \
    (const __attribute__((address_space(1))) unsigned int*)(gp),               \
    (__attribute__((address_space(3))) unsigned int*)(lp), 16, 0, 0)

// ---------- prep: counter zero + LDS-tiled weight transposes + hs cast ----------
// blocks [0,384): Wqkv 64x64 transpose tiles; [384,640): Wo tiles; rest: cast.
__global__ __launch_bounds__(256) void prep_kernel(const float* __restrict__ hs,
                                                   const float* __restrict__ Wq,
                                                   const float* __restrict__ Wk,
                                                   const float* __restrict__ Wv,
                                                   const float* __restrict__ Wo,
                                                   bf16* __restrict__ hsb,
                                                   bf16* __restrict__ WqkvT,
                                                   bf16* __restrict__ WoT,
                                                   int* __restrict__ counter) {
    __shared__ bf16 tl[64 * 66];
    int bidx = blockIdx.x, t = threadIdx.x;
    if (bidx == 0 && t == 0) *counter = 0;
    const int NT_QKV = 16 * 24;    // K/64 x QKVN/64
    const int NT_WO  = 16 * 16;
    if (bidx < NT_QKV + NT_WO) {
        int k0, n0, stride;
        const float* src;
        bf16* dst;
        if (bidx < NT_QKV) {
            int tk = bidx / 24, tn = bidx - tk * 24;
            k0 = tk * 64; n0 = tn * 64;
            if (n0 < 1024)      { src = Wq + n0;          stride = 1024; }
            else if (n0 < 1280) { src = Wk + (n0 - 1024); stride = 256;  }
            else                { src = Wv + (n0 - 1280); stride = 256;  }
            dst = WqkvT + (size_t)n0 * DD + k0;
        } else {
            int j = bidx - NT_QKV;
            int tk = j >> 4, tn = j & 15;
            k0 = tk * 64; n0 = tn * 64;
            src = Wo + n0; stride = 1024;
            dst = WoT + (size_t)n0 * DD + k0;
        }
        int c = t & 63, r0 = (t >> 6) * 16;
        for (int j = 0; j < 16; ++j)
            tl[c * 66 + r0 + j] = (bf16)src[(size_t)(k0 + r0 + j) * stride + c];
        __syncthreads();
        for (int j = 0; j < 16; ++j)
            dst[(size_t)(r0 + j) * DD + c] = tl[(r0 + j) * 66 + c];
    } else {
        int i = (bidx - (NT_QKV + NT_WO)) * 256 + t;   // n4 = 1048576 exactly
        float4 v = ((const float4*)hs)[i];
        ((bf16x4*)hsb)[i] = bf16x4{(bf16)v.x, (bf16)v.y, (bf16)v.z, (bf16)v.w};
    }
}

// ---------- QKV GEMM with fused RoPE + scatter epilogue ----------
// C[4096,1536] = hsb * WqkvT^T; epilogue writes Qr (B,H,S,64), Kr (B,KVH,S,64)
// with RoPE applied, and Vt (B,KVH,64,S) transposed.
__global__ __launch_bounds__(256) void gemm_qkv(const bf16* __restrict__ A,
                                                const bf16* __restrict__ Bt,
                                                const float* __restrict__ cosb,
                                                const float* __restrict__ sinb,
                                                bf16* __restrict__ Qr,
                                                bf16* __restrict__ Kr,
                                                bf16* __restrict__ Vt) {
    __shared__ bf16 As[128 * 32];
    __shared__ bf16 Bs[128 * 32];
    int t = threadIdx.x;
    int wave = t >> 6, lane = t & 63;
    int lm = lane & 15, quad = lane >> 4;
    int m0 = blockIdx.x * 128, n0 = blockIdx.y * 128;
    int wr = wave >> 1, wc = wave & 1;
    const int K = DD;

    int srow = t >> 2;
    int scol = (t & 3) * 8;
    const bf16* ga = A  + (size_t)(m0 + srow) * K + scol;
    const bf16* gb = Bt + (size_t)(n0 + srow) * K + scol;
    bf16* la0 = &As[wave * 512];
    bf16* lb0 = &Bs[wave * 512];

    floatx4 acc[4][4];
    for (int i = 0; i < 4; ++i)
        for (int j = 0; j < 4; ++j) acc[i][j] = floatx4{0.f, 0.f, 0.f, 0.f};

    for (int ks = 0; ks < K; ks += 32) {
        __syncthreads();
        ASYNC16(ga + ks,                la0);
        ASYNC16(ga + ks + (size_t)64*K, la0 + 2048);
        ASYNC16(gb + ks,                lb0);
        ASYNC16(gb + ks + (size_t)64*K, lb0 + 2048);
        __syncthreads();
        bf16x8 af[4], bfr[4];
        for (int mi = 0; mi < 4; ++mi)
            af[mi] = *(const bf16x8*)&As[(wr * 64 + mi * 16 + lm) * 32 + quad * 8];
        for (int ni = 0; ni < 4; ++ni)
            bfr[ni] = *(const bf16x8*)&Bs[(wc * 64 + ni * 16 + lm) * 32 + quad * 8];
        for (int mi = 0; mi < 4; ++mi)
            for (int ni = 0; ni < 4; ++ni)
                acc[mi][ni] = __builtin_amdgcn_mfma_f32_16x16x32_bf16(af[mi], bfr[ni],
                                                                      acc[mi][ni], 0, 0, 0);
    }
    bool odd = lm & 1;
    for (int mi = 0; mi < 4; ++mi)
        for (int ni = 0; ni < 4; ++ni) {
            int c0 = n0 + wc * 64 + ni * 16;
            int row0 = m0 + wr * 64 + mi * 16 + quad * 4;
            floatx4 a = acc[mi][ni];
            int d = (c0 & 63) + lm;        // valid: 1024/1280 are multiples of 64
            if (c0 < 1280) {               // Q or K: apply RoPE
                int ii = d >> 1;
                for (int r = 0; r < 4; ++r) {
                    int row = row0 + r;
                    float self = a[r];
                    float part = __shfl_xor(self, 1);
                    float cc = cosb[(size_t)row * 32 + ii];
                    float sn = sinb[(size_t)row * 32 + ii];
                    float outv = odd ? fmaf(part, sn, self * cc)
                                     : fmaf(self, cc, -part * sn);
                    int s = row & (SS - 1), b = row >> 11;
                    if (c0 < 1024) {
                        int h = c0 >> 6;
                        Qr[((size_t)(b * NH + h) * SS + s) * HD + d] = (bf16)outv;
                    } else {
                        int kvh = (c0 - 1024) >> 6;
                        Kr[((size_t)(b * NKVH + kvh) * SS + s) * HD + d] = (bf16)outv;
                    }
                }
            } else {                       // V: transposed packed store
                int kvh = (c0 - 1280) >> 6;
                bf16x4 pk = {(bf16)a[0], (bf16)a[1], (bf16)a[2], (bf16)a[3]};
                int s0 = row0 & (SS - 1), b = row0 >> 11;
                *(bf16x4*)&Vt[((size_t)(b * NKVH + kvh) * HD + d) * SS + s0] = pk;
            }
        }
}

// ---------- O-projection GEMM (fp32 out) ----------
__global__ __launch_bounds__(256) void gemm_out(const bf16* __restrict__ A,
                                                const bf16* __restrict__ Bt,
                                                float* __restrict__ Cf,
                                                int M, int N, int K) {
    __shared__ bf16 As[128 * 32];
    __shared__ bf16 Bs[128 * 32];
    int t = threadIdx.x;
    int wave = t >> 6, lane = t & 63;
    int lm = lane & 15, quad = lane >> 4;
    int m0 = blockIdx.x * 128, n0 = blockIdx.y * 128;
    int wr = wave >> 1, wc = wave & 1;

    int srow = t >> 2;
    int scol = (t & 3) * 8;
    const bf16* ga = A  + (size_t)(m0 + srow) * K + scol;
    const bf16* gb = Bt + (size_t)(n0 + srow) * K + scol;
    bf16* la0 = &As[wave * 512];
    bf16* lb0 = &Bs[wave * 512];

    floatx4 acc[4][4];
    for (int i = 0; i < 4; ++i)
        for (int j = 0; j < 4; ++j) acc[i][j] = floatx4{0.f, 0.f, 0.f, 0.f};

    for (int ks = 0; ks < K; ks += 32) {
        __syncthreads();
        ASYNC16(ga + ks,                la0);
        ASYNC16(ga + ks + (size_t)64*K, la0 + 2048);
        ASYNC16(gb + ks,                lb0);
        ASYNC16(gb + ks + (size_t)64*K, lb0 + 2048);
        __syncthreads();
        bf16x8 af[4], bfr[4];
        for (int mi = 0; mi < 4; ++mi)
            af[mi] = *(const bf16x8*)&As[(wr * 64 + mi * 16 + lm) * 32 + quad * 8];
        for (int ni = 0; ni < 4; ++ni)
            bfr[ni] = *(const bf16x8*)&Bs[(wc * 64 + ni * 16 + lm) * 32 + quad * 8];
        for (int mi = 0; mi < 4; ++mi)
            for (int ni = 0; ni < 4; ++ni)
                acc[mi][ni] = __builtin_amdgcn_mfma_f32_16x16x32_bf16(af[mi], bfr[ni],
                                                                      acc[mi][ni], 0, 0, 0);
    }
    for (int mi = 0; mi < 4; ++mi)
        for (int ni = 0; ni < 4; ++ni)
            for (int r = 0; r < 4; ++r) {
                size_t row = (size_t)(m0 + wr * 64 + mi * 16 + quad * 4 + r);
                Cf[row * N + n0 + wc * 64 + ni * 16 + lm] = acc[mi][ni][r];
            }
}

// ---------- flash attention: persistent WGs + atomic work queue ----------
// Item = (bh, q-block of 64 queries), longest q-blocks first. 4 waves/WG,
// K/V 64-key chunks staged once per WG (global_load_lds, XOR swizzle).
__global__ __launch_bounds__(256, 4) void attn_kernel(const bf16* __restrict__ Qr,
                                                      const bf16* __restrict__ Kr,
                                                      const bf16* __restrict__ Vt,
                                                      bf16* __restrict__ ctx,
                                                      int* __restrict__ counter) {
    __shared__ __align__(16) bf16 kv[8192];          // K: [0,4096) V: [4096,8192)
    __shared__ __align__(16) bf16 p_lds[4][16][72];
    __shared__ int s_item;
    int t = threadIdx.x;
    int wave = t >> 6, lane = t & 63;
    int lm = lane & 15, quad = lane >> 4;

    int srow = t >> 3;
    int scol = ((t & 7) ^ (srow & 7)) * 8;
    bf16* lds_w = kv + wave * 512;

    for (;;) {
        __syncthreads();                             // prev item done with kv/s_item
        if (t == 0) s_item = atomicAdd(counter, 1);
        __syncthreads();
        int it = s_item;
        if (it >= NITEMS) break;

        int qb = 31 - (it >> 5);                     // longest first
        int bh = it & 31;
        int h = bh & (NH - 1), b = bh >> 4;
        int kvh = h >> 2;
        int q0w = qb * 64 + wave * 16;

        const bf16* qp = Qr + ((size_t)(b * NH + h) * SS + q0w + lm) * HD;
        bf16x8 qf0 = *(const bf16x8*)(qp + quad * 8);
        bf16x8 qf1 = *(const bf16x8*)(qp + 32 + quad * 8);
        const bf16* kbase = Kr + (size_t)(b * NKVH + kvh) * SS * HD;
        const bf16* vbase = Vt + (size_t)(b * NKVH + kvh) * HD * SS;
        const bf16* gk = kbase + (size_t)srow * HD + scol;
        const bf16* gv = vbase + (size_t)srow * SS + scol;

        float m_prev = -1e30f, l_prev = 0.f;
        floatx4 o[4];
        for (int dt = 0; dt < 4; ++dt) o[dt] = floatx4{0.f, 0.f, 0.f, 0.f};

        int nch = qb + 1;
        for (int ck = 0; ck < nch; ++ck) {
            int kb = ck * 64;
            __syncthreads();
            ASYNC16(gk + (size_t)kb * HD,        lds_w);
            ASYNC16(gk + (size_t)(kb + 32) * HD, lds_w + 2048);
            ASYNC16(gv + kb,                     lds_w + 4096);
            ASYNC16(gv + (size_t)32 * SS + kb,   lds_w + 6144);
            __syncthreads();

            floatx4 st[4];
            for (int tt = 0; tt < 4; ++tt) {
                int kk = tt * 16 + lm;
                const bf16* krow = kv + kk * 64;
                bf16x8 k0 = *(const bf16x8*)(krow + ((quad ^ (lm & 7)) * 8));
                bf16x8 k1 = *(const bf16x8*)(krow + (((quad + 4) ^ (lm & 7)) * 8));
                floatx4 s = {0.f, 0.f, 0.f, 0.f};
                s = __builtin_amdgcn_mfma_f32_16x16x32_bf16(k0, qf0, s, 0, 0, 0);
                s = __builtin_amdgcn_mfma_f32_16x16x32_bf16(k1, qf1, s, 0, 0, 0);
                st[tt] = s;
            }
            bool needmask = (ck == nch - 1);
            float mx = -1e30f;
            for (int tt = 0; tt < 4; ++tt)
                for (int r = 0; r < 4; ++r) {
                    float v = st[tt][r] * SCALE;
                    if (needmask && (kb + tt * 16 + quad * 4 + r > q0w + lm)) v = -1e30f;
                    st[tt][r] = v;
                    mx = fmaxf(mx, v);
                }
            mx = fmaxf(mx, __shfl_xor(mx, 16));
            mx = fmaxf(mx, __shfl_xor(mx, 32));
            float m_new = fmaxf(m_prev, mx);
            float alpha = __expf(m_prev - m_new);
            m_prev = m_new;
            float ls = 0.f;
            for (int tt = 0; tt < 4; ++tt)
                for (int r = 0; r < 4; ++r) {
                    float p = __expf(st[tt][r] - m_new);
                    st[tt][r] = p;
                    ls += p;
                }
            ls += __shfl_xor(ls, 16);
            ls += __shfl_xor(ls, 32);
            l_prev = l_prev * alpha + ls;

            for (int tt = 0; tt < 4; ++tt) {
                bf16x4 pk = {(bf16)st[tt][0], (bf16)st[tt][1],
                             (bf16)st[tt][2], (bf16)st[tt][3]};
                *(bf16x4*)&p_lds[wave][lm][tt * 16 + quad * 4] = pk;
            }
            for (int r = 0; r < 4; ++r) {
                float a = __shfl(alpha, quad * 4 + r);
                for (int dt = 0; dt < 4; ++dt) o[dt][r] *= a;
            }
            bf16x8 pa0 = *(const bf16x8*)&p_lds[wave][lm][quad * 8];
            bf16x8 pa1 = *(const bf16x8*)&p_lds[wave][lm][32 + quad * 8];
            for (int dt = 0; dt < 4; ++dt) {
                int d = dt * 16 + lm;
                const bf16* vrow = kv + 4096 + d * 64;
                bf16x8 v0 = *(const bf16x8*)(vrow + ((quad ^ (lm & 7)) * 8));
                bf16x8 v1 = *(const bf16x8*)(vrow + (((quad + 4) ^ (lm & 7)) * 8));
                o[dt] = __builtin_amdgcn_mfma_f32_16x16x32_bf16(pa0, v0, o[dt], 0, 0, 0);
                o[dt] = __builtin_amdgcn_mfma_f32_16x16x32_bf16(pa1, v1, o[dt], 0, 0, 0);
            }
        }
        float linv = 1.f / l_prev;
        for (int r = 0; r < 4; ++r) {
            float inv = __shfl(linv, quad * 4 + r);
            int qi = q0w + quad * 4 + r;
            for (int dt = 0; dt < 4; ++dt)
                ctx[((size_t)b * SS + qi) * DD + h * HD + dt * 16 + lm] =
                    (bf16)(o[dt][r] * inv);
        }
    }
}

// ---------- host ----------
extern "C" void kernel_launch(void* const* d_in, const int* in_sizes, int n_in,
                              void* d_out, int out_size, void* d_ws, size_t ws_size,
                              hipStream_t stream) {
    const float* hs   = (const float*)d_in[0];
    const float* cosb = (const float*)d_in[1];
    const float* sinb = (const float*)d_in[2];
    const float* Wq = (const float*)d_in[4];
    const float* Wk = (const float*)d_in[5];
    const float* Wv = (const float*)d_in[6];
    const float* Wo = (const float*)d_in[7];
    float* out = (float*)d_out;

    char* ws = (char*)d_ws;
    size_t off = 0;
    auto alloc = [&](size_t bytes) {
        char* p = ws + off;
        off += (bytes + 255) & ~(size_t)255;
        return p;
    };
    const size_t MT = (size_t)BB * SS;                    // 4096 tokens
    int*  counter = (int*)alloc(256);
    bf16* hsb     = (bf16*)alloc(MT * DD * 2);
    bf16* WqkvT   = (bf16*)alloc((size_t)QKVN * DD * 2);
    bf16* WoT     = (bf16*)alloc((size_t)DD * DD * 2);
    bf16* Qr      = (bf16*)alloc(MT * DD * 2);
    bf16* Kr      = (bf16*)alloc(MT * 256 * 2);
    bf16* Vt      = (bf16*)alloc(MT * 256 * 2);
    bf16* ctx     = (bf16*)alloc(MT * DD * 2);

    // 1. prep: counter zero + tiled weight transposes + hs cast
    prep_kernel<<<384 + 256 + 4096, 256, 0, stream>>>(hs, Wq, Wk, Wv, Wo,
                                                      hsb, WqkvT, WoT, counter);
    // 2. fused QKV projection + RoPE + V scatter
    gemm_qkv<<<dim3(MT / 128, QKVN / 128), 256, 0, stream>>>(hsb, WqkvT, cosb, sinb,
                                                             Qr, Kr, Vt);
    // 3. attention (persistent WGs, work queue)
    attn_kernel<<<1536, 256, 0, stream>>>(Qr, Kr, Vt, ctx, counter);
    // 4. output projection (fp32 out)
    gemm_out<<<dim3(MT / 128, DD / 128), 256, 0, stream>>>(ctx, WoT, out,
                                                           (int)MT, DD, DD);

    (void)in_sizes; (void)n_in; (void)out_size; (void)ws_size;
}

// Round 5
// 188.631 us; speedup vs baseline: 3.5103x; 1.1178x over previous
//
#include <hip/hip_runtime.h>

#define BB 2
#define SS 2048
#define DD 1024
#define NH 16
#define NKVH 4
#define HD 64
#define QKVN 1536          // fused Wqkv output columns: 1024 q | 256 k | 256 v
#define SCALE 0.125f       // 64^-0.5, exact power of 2 -> folded into Q frags

typedef __bf16 bf16;
typedef __bf16 bf16x4 __attribute__((ext_vector_type(4)));
typedef __bf16 bf16x8 __attribute__((ext_vector_type(8)));
typedef float floatx4 __attribute__((ext_vector_type(4)));

#define ASYNC16(gp, lp) __builtin_amdgcn_global_load_lds(                      \
    (const __attribute__((address_space(1))) unsigned int*)(gp),               \
    (__attribute__((address_space(3))) unsigned int*)(lp), 16, 0, 0)

// ---------- prep: LDS-tiled weight transposes + hs cast ----------
__global__ __launch_bounds__(256) void prep_kernel(const float* __restrict__ hs,
                                                   const float* __restrict__ Wq,
                                                   const float* __restrict__ Wk,
                                                   const float* __restrict__ Wv,
                                                   const float* __restrict__ Wo,
                                                   bf16* __restrict__ hsb,
                                                   bf16* __restrict__ WqkvT,
                                                   bf16* __restrict__ WoT) {
    __shared__ bf16 tl[64 * 66];
    int bidx = blockIdx.x, t = threadIdx.x;
    const int NT_QKV = 16 * 24;    // K/64 x QKVN/64
    const int NT_WO  = 16 * 16;
    if (bidx < NT_QKV + NT_WO) {
        int k0, n0, stride;
        const float* src;
        bf16* dst;
        if (bidx < NT_QKV) {
            int tk = bidx / 24, tn = bidx - tk * 24;
            k0 = tk * 64; n0 = tn * 64;
            if (n0 < 1024)      { src = Wq + n0;          stride = 1024; }
            else if (n0 < 1280) { src = Wk + (n0 - 1024); stride = 256;  }
            else                { src = Wv + (n0 - 1280); stride = 256;  }
            dst = WqkvT + (size_t)n0 * DD + k0;
        } else {
            int j = bidx - NT_QKV;
            int tk = j >> 4, tn = j & 15;
            k0 = tk * 64; n0 = tn * 64;
            src = Wo + n0; stride = 1024;
            dst = WoT + (size_t)n0 * DD + k0;
        }
        int c = t & 63, r0 = (t >> 6) * 16;
        for (int j = 0; j < 16; ++j)
            tl[c * 66 + r0 + j] = (bf16)src[(size_t)(k0 + r0 + j) * stride + c];
        __syncthreads();
        for (int j = 0; j < 16; ++j)
            dst[(size_t)(r0 + j) * DD + c] = tl[(r0 + j) * 66 + c];
    } else {
        int i = (bidx - (NT_QKV + NT_WO)) * 256 + t;   // n4 = 1048576 exactly
        float4 v = ((const float4*)hs)[i];
        ((bf16x4*)hsb)[i] = bf16x4{(bf16)v.x, (bf16)v.y, (bf16)v.z, (bf16)v.w};
    }
}

// ---------- QKV GEMM with fused RoPE + scatter epilogue ----------
__global__ __launch_bounds__(256) void gemm_qkv(const bf16* __restrict__ A,
                                                const bf16* __restrict__ Bt,
                                                const float* __restrict__ cosb,
                                                const float* __restrict__ sinb,
                                                bf16* __restrict__ Qr,
                                                bf16* __restrict__ Kr,
                                                bf16* __restrict__ Vt) {
    __shared__ bf16 As[128 * 32];
    __shared__ bf16 Bs[128 * 32];
    int t = threadIdx.x;
    int wave = t >> 6, lane = t & 63;
    int lm = lane & 15, quad = lane >> 4;
    int m0 = blockIdx.x * 128, n0 = blockIdx.y * 128;
    int wr = wave >> 1, wc = wave & 1;
    const int K = DD;

    int srow = t >> 2;
    int scol = (t & 3) * 8;
    const bf16* ga = A  + (size_t)(m0 + srow) * K + scol;
    const bf16* gb = Bt + (size_t)(n0 + srow) * K + scol;
    bf16* la0 = &As[wave * 512];
    bf16* lb0 = &Bs[wave * 512];

    floatx4 acc[4][4];
    for (int i = 0; i < 4; ++i)
        for (int j = 0; j < 4; ++j) acc[i][j] = floatx4{0.f, 0.f, 0.f, 0.f};

    for (int ks = 0; ks < K; ks += 32) {
        __syncthreads();
        ASYNC16(ga + ks,                la0);
        ASYNC16(ga + ks + (size_t)64*K, la0 + 2048);
        ASYNC16(gb + ks,                lb0);
        ASYNC16(gb + ks + (size_t)64*K, lb0 + 2048);
        __syncthreads();
        bf16x8 af[4], bfr[4];
        for (int mi = 0; mi < 4; ++mi)
            af[mi] = *(const bf16x8*)&As[(wr * 64 + mi * 16 + lm) * 32 + quad * 8];
        for (int ni = 0; ni < 4; ++ni)
            bfr[ni] = *(const bf16x8*)&Bs[(wc * 64 + ni * 16 + lm) * 32 + quad * 8];
        for (int mi = 0; mi < 4; ++mi)
            for (int ni = 0; ni < 4; ++ni)
                acc[mi][ni] = __builtin_amdgcn_mfma_f32_16x16x32_bf16(af[mi], bfr[ni],
                                                                      acc[mi][ni], 0, 0, 0);
    }
    bool odd = lm & 1;
    for (int mi = 0; mi < 4; ++mi)
        for (int ni = 0; ni < 4; ++ni) {
            int c0 = n0 + wc * 64 + ni * 16;
            int row0 = m0 + wr * 64 + mi * 16 + quad * 4;
            floatx4 a = acc[mi][ni];
            int d = (c0 & 63) + lm;
            if (c0 < 1280) {               // Q or K: apply RoPE
                int ii = d >> 1;
                for (int r = 0; r < 4; ++r) {
                    int row = row0 + r;
                    float self = a[r];
                    float part = __shfl_xor(self, 1);
                    float cc = cosb[(size_t)row * 32 + ii];
                    float sn = sinb[(size_t)row * 32 + ii];
                    float outv = odd ? fmaf(part, sn, self * cc)
                                     : fmaf(self, cc, -part * sn);
                    int s = row & (SS - 1), b = row >> 11;
                    if (c0 < 1024) {
                        int h = c0 >> 6;
                        Qr[((size_t)(b * NH + h) * SS + s) * HD + d] = (bf16)outv;
                    } else {
                        int kvh = (c0 - 1024) >> 6;
                        Kr[((size_t)(b * NKVH + kvh) * SS + s) * HD + d] = (bf16)outv;
                    }
                }
            } else {                       // V: transposed packed store
                int kvh = (c0 - 1280) >> 6;
                bf16x4 pk = {(bf16)a[0], (bf16)a[1], (bf16)a[2], (bf16)a[3]};
                int s0 = row0 & (SS - 1), b = row0 >> 11;
                *(bf16x4*)&Vt[((size_t)(b * NKVH + kvh) * HD + d) * SS + s0] = pk;
            }
        }
}

// ---------- O-projection GEMM (fp32 out) ----------
__global__ __launch_bounds__(256) void gemm_out(const bf16* __restrict__ A,
                                                const bf16* __restrict__ Bt,
                                                float* __restrict__ Cf,
                                                int M, int N, int K) {
    __shared__ bf16 As[128 * 32];
    __shared__ bf16 Bs[128 * 32];
    int t = threadIdx.x;
    int wave = t >> 6, lane = t & 63;
    int lm = lane & 15, quad = lane >> 4;
    int m0 = blockIdx.x * 128, n0 = blockIdx.y * 128;
    int wr = wave >> 1, wc = wave & 1;

    int srow = t >> 2;
    int scol = (t & 3) * 8;
    const bf16* ga = A  + (size_t)(m0 + srow) * K + scol;
    const bf16* gb = Bt + (size_t)(n0 + srow) * K + scol;
    bf16* la0 = &As[wave * 512];
    bf16* lb0 = &Bs[wave * 512];

    floatx4 acc[4][4];
    for (int i = 0; i < 4; ++i)
        for (int j = 0; j < 4; ++j) acc[i][j] = floatx4{0.f, 0.f, 0.f, 0.f};

    for (int ks = 0; ks < K; ks += 32) {
        __syncthreads();
        ASYNC16(ga + ks,                la0);
        ASYNC16(ga + ks + (size_t)64*K, la0 + 2048);
        ASYNC16(gb + ks,                lb0);
        ASYNC16(gb + ks + (size_t)64*K, lb0 + 2048);
        __syncthreads();
        bf16x8 af[4], bfr[4];
        for (int mi = 0; mi < 4; ++mi)
            af[mi] = *(const bf16x8*)&As[(wr * 64 + mi * 16 + lm) * 32 + quad * 8];
        for (int ni = 0; ni < 4; ++ni)
            bfr[ni] = *(const bf16x8*)&Bs[(wc * 64 + ni * 16 + lm) * 32 + quad * 8];
        for (int mi = 0; mi < 4; ++mi)
            for (int ni = 0; ni < 4; ++ni)
                acc[mi][ni] = __builtin_amdgcn_mfma_f32_16x16x32_bf16(af[mi], bfr[ni],
                                                                      acc[mi][ni], 0, 0, 0);
    }
    for (int mi = 0; mi < 4; ++mi)
        for (int ni = 0; ni < 4; ++ni)
            for (int r = 0; r < 4; ++r) {
                size_t row = (size_t)(m0 + wr * 64 + mi * 16 + quad * 4 + r);
                Cf[row * N + n0 + wc * 64 + ni * 16 + lm] = acc[mi][ni][r];
            }
}

// ---------- flash attention: XCD-pinned static items, double-buffered K/V ----------
// bid&7 = (b*4+kvh) -> one (b,kvh) group per XCD (K/V+Q become L2-resident).
// 4 waves / 64 queries per WG; 64-key chunks; chunk k+1 staged while computing k
// -> single barrier per chunk, vmcnt drain hidden behind compute.
__global__ __launch_bounds__(256, 3) void attn_kernel(const bf16* __restrict__ Qr,
                                                      const bf16* __restrict__ Kr,
                                                      const bf16* __restrict__ Vt,
                                                      bf16* __restrict__ ctx) {
    __shared__ __align__(16) bf16 kv[2][8192];       // [buf][ K:4096 | V:4096 ]
    __shared__ __align__(16) bf16 p_lds[4][16][72];
    int t = threadIdx.x;
    int wave = t >> 6, lane = t & 63;
    int lm = lane & 15, quad = lane >> 4;

    int bid = blockIdx.x;
    int g = bid & 7;                   // XCD group = b*4 + kvh
    int j = bid >> 3;                  // 0..127 within group
    int b = g >> 2, kvh = g & 3;
    int h = kvh * 4 + (j & 3);
    int qb = 31 - (j >> 2);            // longest q-blocks dispatch first
    int q0w = qb * 64 + wave * 16;

    // Q fragments, pre-scaled by SCALE (0.125 = 2^-3, exact in bf16)
    const bf16* qp = Qr + ((size_t)(b * NH + h) * SS + q0w + lm) * HD;
    bf16x8 qf0 = *(const bf16x8*)(qp + quad * 8);
    bf16x8 qf1 = *(const bf16x8*)(qp + 32 + quad * 8);
    for (int i = 0; i < 8; ++i) {
        qf0[i] = (bf16)((float)qf0[i] * SCALE);
        qf1[i] = (bf16)((float)qf1[i] * SCALE);
    }

    const bf16* kbase = Kr + (size_t)(b * NKVH + kvh) * SS * HD;
    const bf16* vbase = Vt + (size_t)(b * NKVH + kvh) * HD * SS;
    int srow = t >> 3;                         // 0..31
    int scol = ((t & 7) ^ (srow & 7)) * 8;     // XOR swizzle (async-LDS forbids pads)
    const bf16* gk = kbase + (size_t)srow * HD + scol;
    const bf16* gv = vbase + (size_t)srow * SS + scol;

    float m_prev = -1e30f, l_prev = 0.f;
    floatx4 o[4];
    for (int dt = 0; dt < 4; ++dt) o[dt] = floatx4{0.f, 0.f, 0.f, 0.f};

    int nch = qb + 1;
    // stage chunk 0 into buf 0
    {
        bf16* l = &kv[0][0] + wave * 512;
        ASYNC16(gk,                     l);
        ASYNC16(gk + (size_t)32 * HD,   l + 2048);
        ASYNC16(gv,                     l + 4096);
        ASYNC16(gv + (size_t)32 * SS,   l + 6144);
    }
    __syncthreads();                           // buf0 staged (vmcnt drained)

    for (int ck = 0; ck < nch; ++ck) {
        int kb = ck * 64;
        if (ck + 1 < nch) {                    // prefetch next chunk into other buf
            int kn = kb + 64;
            bf16* l = &kv[(ck + 1) & 1][0] + wave * 512;
            ASYNC16(gk + (size_t)kn * HD,        l);
            ASYNC16(gk + (size_t)(kn + 32) * HD, l + 2048);
            ASYNC16(gv + kn,                     l + 4096);
            ASYNC16(gv + (size_t)32 * SS + kn,   l + 6144);
        }
        const bf16* kbuf = &kv[ck & 1][0];
        const bf16* vbuf = kbuf + 4096;

        // S^T = K·Q^T (rows = keys, cols = queries; lane lm = its query)
        floatx4 st[4];
        for (int tt = 0; tt < 4; ++tt) {
            int kk = tt * 16 + lm;             // kk&7 == lm&7
            const bf16* krow = kbuf + kk * 64;
            bf16x8 k0 = *(const bf16x8*)(krow + ((quad ^ (lm & 7)) * 8));
            bf16x8 k1 = *(const bf16x8*)(krow + (((quad + 4) ^ (lm & 7)) * 8));
            floatx4 s = {0.f, 0.f, 0.f, 0.f};
            s = __builtin_amdgcn_mfma_f32_16x16x32_bf16(k0, qf0, s, 0, 0, 0);
            s = __builtin_amdgcn_mfma_f32_16x16x32_bf16(k1, qf1, s, 0, 0, 0);
            st[tt] = s;
        }
        if (ck == nch - 1) {                   // causal mask, final chunk only
            for (int tt = 0; tt < 4; ++tt)
                for (int r = 0; r < 4; ++r)
                    if (kb + tt * 16 + quad * 4 + r > q0w + lm) st[tt][r] = -1e30f;
        }
        // tree max over 16 regs + 2 quad shuffles
        float tm[4];
        for (int tt = 0; tt < 4; ++tt)
            tm[tt] = fmaxf(fmaxf(st[tt][0], st[tt][1]), fmaxf(st[tt][2], st[tt][3]));
        float mx = fmaxf(fmaxf(tm[0], tm[1]), fmaxf(tm[2], tm[3]));
        mx = fmaxf(mx, __shfl_xor(mx, 16));
        mx = fmaxf(mx, __shfl_xor(mx, 32));
        float m_new = fmaxf(m_prev, mx);
        float alpha = __expf(m_prev - m_new);
        m_prev = m_new;
        // exp + tree sum
        float ts[4];
        for (int tt = 0; tt < 4; ++tt) {
            float p0 = __expf(st[tt][0] - m_new);
            float p1 = __expf(st[tt][1] - m_new);
            float p2 = __expf(st[tt][2] - m_new);
            float p3 = __expf(st[tt][3] - m_new);
            st[tt] = floatx4{p0, p1, p2, p3};
            ts[tt] = (p0 + p1) + (p2 + p3);
        }
        float ls = (ts[0] + ts[1]) + (ts[2] + ts[3]);
        ls += __shfl_xor(ls, 16);
        ls += __shfl_xor(ls, 32);
        l_prev = l_prev * alpha + ls;

        // P^T -> A-layout via wave-private LDS (no barrier)
        for (int tt = 0; tt < 4; ++tt) {
            bf16x4 pk = {(bf16)st[tt][0], (bf16)st[tt][1],
                         (bf16)st[tt][2], (bf16)st[tt][3]};
            *(bf16x4*)&p_lds[wave][lm][tt * 16 + quad * 4] = pk;
        }
        for (int r = 0; r < 4; ++r) {
            float a = __shfl(alpha, quad * 4 + r);
            for (int dt = 0; dt < 4; ++dt) o[dt][r] *= a;
        }
        bf16x8 pa0 = *(const bf16x8*)&p_lds[wave][lm][quad * 8];
        bf16x8 pa1 = *(const bf16x8*)&p_lds[wave][lm][32 + quad * 8];
        for (int dt = 0; dt < 4; ++dt) {
            int d = dt * 16 + lm;              // d&7 == lm&7
            const bf16* vrow = vbuf + d * 64;
            bf16x8 v0 = *(const bf16x8*)(vrow + ((quad ^ (lm & 7)) * 8));
            bf16x8 v1 = *(const bf16x8*)(vrow + (((quad + 4) ^ (lm & 7)) * 8));
            o[dt] = __builtin_amdgcn_mfma_f32_16x16x32_bf16(pa0, v0, o[dt], 0, 0, 0);
            o[dt] = __builtin_amdgcn_mfma_f32_16x16x32_bf16(pa1, v1, o[dt], 0, 0, 0);
        }
        __syncthreads();   // all waves done with kbuf/vbuf; next-chunk loads drained
    }
    float linv = 1.f / l_prev;
    for (int r = 0; r < 4; ++r) {
        float inv = __shfl(linv, quad * 4 + r);
        int qi = q0w + quad * 4 + r;
        for (int dt = 0; dt < 4; ++dt)
            ctx[((size_t)b * SS + qi) * DD + h * HD + dt * 16 + lm] =
                (bf16)(o[dt][r] * inv);
    }
}

// ---------- host ----------
extern "C" void kernel_launch(void* const* d_in, const int* in_sizes, int n_in,
                              void* d_out, int out_size, void* d_ws, size_t ws_size,
                              hipStream_t stream) {
    const float* hs   = (const float*)d_in[0];
    const float* cosb = (const float*)d_in[1];
    const float* sinb = (const float*)d_in[2];
    const float* Wq = (const float*)d_in[4];
    const float* Wk = (const float*)d_in[5];
    const float* Wv = (const float*)d_in[6];
    const float* Wo = (const float*)d_in[7];
    float* out = (float*)d_out;

    char* ws = (char*)d_ws;
    size_t off = 0;
    auto alloc = [&](size_t bytes) {
        char* p = ws + off;
        off += (bytes + 255) & ~(size_t)255;
        return p;
    };
    const size_t MT = (size_t)BB * SS;                    // 4096 tokens
    bf16* hsb     = (bf16*)alloc(MT * DD * 2);
    bf16* WqkvT   = (bf16*)alloc((size_t)QKVN * DD * 2);
    bf16* WoT     = (bf16*)alloc((size_t)DD * DD * 2);
    bf16* Qr      = (bf16*)alloc(MT * DD * 2);
    bf16* Kr      = (bf16*)alloc(MT * 256 * 2);
    bf16* Vt      = (bf16*)alloc(MT * 256 * 2);
    bf16* ctx     = (bf16*)alloc(MT * DD * 2);

    // 1. prep: tiled weight transposes + hs cast
    prep_kernel<<<384 + 256 + 4096, 256, 0, stream>>>(hs, Wq, Wk, Wv, Wo,
                                                      hsb, WqkvT, WoT);
    // 2. fused QKV projection + RoPE + V scatter
    gemm_qkv<<<dim3(MT / 128, QKVN / 128), 256, 0, stream>>>(hsb, WqkvT, cosb, sinb,
                                                             Qr, Kr, Vt);
    // 3. attention (1024 WGs: bid&7 = XCD group, longest-first within group)
    attn_kernel<<<1024, 256, 0, stream>>>(Qr, Kr, Vt, ctx);
    // 4. output projection (fp32 out)
    gemm_out<<<dim3(MT / 128, DD / 128), 256, 0, stream>>>(ctx, WoT, out,
                                                           (int)MT, DD, DD);

    (void)in_sizes; (void)n_in; (void)out_size; (void)ws_size;
}